// Round 8
// baseline (7706.525 us; speedup 1.0000x reference)
//
#include <hip/hip_runtime.h>
#include <math.h>

// ---------------------------------------------------------------------------
// SequencePredictorGRU — fused persistent kernel, fp16 MFMA, fp32 accum.
// R8 = R7's clean frag-order layout + R3's single-buffer structure + the
// verified 128-VGPR pin, to get 2 blocks/CU (4 waves/SIMD, the R5/R6 lesson)
// WITHOUT spilling:
//  - 512 threads, __launch_bounds__(512,2) -> 128 VGPR budget (verified R1/R2/R7)
//  - single h buffer [64][512] f16 in MFMA B-fragment order (64KB); h_new held
//    in 32 regs (hnh, statically indexed via full q-unroll — rule #20) across
//    the read/write barrier. LDS ~69KB -> 2 blocks/CU -> 4 waves/SIMD.
//  - init t1 (64x1024) as two 32-row halves aliasing the h region; h0 halves
//    held in regs (statically indexed via full hh-unroll).
//  - blend coefficients packed f16 c7[7][512] (14 regs instead of 28).
// Frag-order addr: chunk((k>>5)*nmt + (m>>4)) * 1024 + line((m&15)+((k>>3)&3)*16)*16
//  + (k&7)*2; B-frag reads are base + chunk*1024 + lane*16 (linear, conflict-free).
// MFMA 16x16x32 layouts (verified R1-R7):
//   A: row=l&15, k=(l>>4)*8+i     B: col=l&15, k=(l>>4)*8+i
//   D: col=l&15 (-> m row), row=(l>>4)*4+r (-> j, contiguous quad)
// ---------------------------------------------------------------------------

typedef _Float16 f16;
typedef _Float16 f16x4 __attribute__((ext_vector_type(4)));
typedef _Float16 f16x8 __attribute__((ext_vector_type(8)));
typedef float f32x4 __attribute__((ext_vector_type(4)));

#define TSTEPS 20

__device__ __forceinline__ float sigm(float v) { return 1.0f / (1.0f + __expf(-v)); }
__device__ __forceinline__ float tanh_s(float v) {
  float e = __expf(-2.0f * fabsf(v));
  float r = (1.0f - e) / (1.0f + e);
  return copysignf(r, v);
}
__device__ __forceinline__ float gelu_e(float v) {
  return 0.5f * v * (1.0f + erff(v * 0.70710678118654752f));
}
__device__ __forceinline__ void st4(float* d, float4 v) {
  d[0] = v.x; d[1] = v.y; d[2] = v.z; d[3] = v.w;
}

// frag-order address, 64-row h buffer (chunks (k>>5)*4 + m>>4, 64KB)
__device__ __forceinline__ int fa(int m, int k) {
  return (((k >> 5) * 4 + (m >> 4)) << 10) + (((m & 15) + ((k >> 3) & 3) * 16) << 4) + ((k & 7) * 2);
}
// frag-order address, 32-row t1 half (chunks (k>>5)*2 + (m>>4), 64KB for k<1024)
__device__ __forceinline__ int fa32(int m, int k) {
  return (((k >> 5) * 2 + ((m >> 4) & 1)) << 10) + (((m & 15) + ((k >> 3) & 3) * 16) << 4) + ((k & 7) * 2);
}

// ---------------------------------------------------------------------------
// Prologue: fp16 weights (K-contiguous) + packed f16 gate coefficients.
// c7 layout [7][512]: 0 Wih_r, 1 Wih_z, 2 Wih_n, 3 bih_r+bhh_r, 4 bih_z+bhh_z,
//                     5 bih_n, 6 bhh_n
// ---------------------------------------------------------------------------
__global__ void cvt_weights(const float* __restrict__ W1, const float* __restrict__ W2,
                            const float* __restrict__ Whh, const float* __restrict__ Wo1,
                            const float* __restrict__ Wih, const float* __restrict__ bih,
                            const float* __restrict__ bhh,
                            f16* __restrict__ w1t, f16* __restrict__ w2t,
                            f16* __restrict__ whh, f16* __restrict__ wo1t,
                            f16* __restrict__ c7) {
  int i = blockIdx.x * 256 + threadIdx.x;
  if (i < 163840) { int n = i / 160; int k = i - n * 160; w1t[i] = (f16)W1[k * 1024 + n]; return; }
  i -= 163840;
  if (i < 524288) { int n = i >> 10; int k = i & 1023; w2t[i] = (f16)W2[k * 512 + n]; return; }
  i -= 524288;
  if (i < 786432) { whh[i] = (f16)Whh[i]; return; }
  i -= 786432;
  if (i < 131072) { int o = i >> 9; int k = i & 511; wo1t[i] = (f16)Wo1[k * 256 + o]; return; }
  i -= 131072;
  if (i < 3584) {
    const int which = i >> 9, j = i & 511;
    float v;
    if (which == 0) v = Wih[j];
    else if (which == 1) v = Wih[512 + j];
    else if (which == 2) v = Wih[1024 + j];
    else if (which == 3) v = bih[j] + bhh[j];
    else if (which == 4) v = bih[512 + j] + bhh[512 + j];
    else if (which == 5) v = bih[1024 + j];
    else v = bhh[1024 + j];
    c7[i] = (f16)v;
  }
}

// ---------------------------------------------------------------------------
// Main fused kernel: 512 threads = 8 waves, 64 rows/block, 2 blocks/CU.
// ---------------------------------------------------------------------------
__global__ __launch_bounds__(512, 2)
void gru_main(
    const float* __restrict__ zq, const float* __restrict__ fpr,
    const float* __restrict__ b1, const float* __restrict__ g1, const float* __restrict__ be1,
    const float* __restrict__ b2, const float* __restrict__ stok,
    const float* __restrict__ bo1, const float* __restrict__ go, const float* __restrict__ beo,
    const float* __restrict__ Wo2, const float* __restrict__ bo2,
    const f16* __restrict__ w1t, const f16* __restrict__ w2t,
    const f16* __restrict__ whh, const f16* __restrict__ wo1t,
    const f16* __restrict__ c7,
    float* __restrict__ out) {
  __shared__ __align__(16) unsigned char sm[65536];  // h [64][512] frag order / t1 half
  __shared__ float sm_s[256], sm_ss[256], sm_yp[256];
  __shared__ float sm_x[64];

  const int tid = threadIdx.x;
  const int w = tid >> 6;        // 0..7
  const int lane = tid & 63;
  const int l16 = lane & 15;
  const int l4 = lane >> 4;
  const int R0 = blockIdx.x * 64;

  const float bo2v = bo2[0];
  if (tid < 64) sm_x[tid] = stok[0];

  // ======================= init_mlp (two 32-row halves) ====================
  f16x4 h0h[2][4][2];  // [hh][pp][mt] — statically indexed (loops fully unrolled)

  #pragma unroll
  for (int hh = 0; hh < 2; ++hh) {
    const int RH = R0 + hh * 32;
    // ---- G0a: t1 = cat(zq,fpr) @ W1 + b1 -> t1 half (frag order) ----------
    #pragma unroll 1
    for (int p = 0; p < 4; ++p) {
      #pragma unroll 1
      for (int jh = 0; jh < 2; ++jh) {
        const int jq0 = w * 128 + p * 32 + jh * 16;
        f32x4 acc[2];
        #pragma unroll
        for (int mt = 0; mt < 2; ++mt) acc[mt] = (f32x4){0.f, 0.f, 0.f, 0.f};
        #pragma unroll
        for (int kf = 0; kf < 5; ++kf) {
          const int k0 = kf * 32 + l4 * 8;
          f16x8 B[2];
          #pragma unroll
          for (int mt = 0; mt < 2; ++mt) {
            const int gm = RH + mt * 16 + l16;
            const float* src = (kf < 4) ? (zq + gm * 128 + k0) : (fpr + gm * 32 + (k0 - 128));
            float4 v0 = *(const float4*)src;
            float4 v1 = *(const float4*)(src + 4);
            f16x8 b;
            b[0] = (f16)v0.x; b[1] = (f16)v0.y; b[2] = (f16)v0.z; b[3] = (f16)v0.w;
            b[4] = (f16)v1.x; b[5] = (f16)v1.y; b[6] = (f16)v1.z; b[7] = (f16)v1.w;
            B[mt] = b;
          }
          const f16x8 A = *(const f16x8*)(w1t + (jq0 + l16) * 160 + k0);
          #pragma unroll
          for (int mt = 0; mt < 2; ++mt)
            acc[mt] = __builtin_amdgcn_mfma_f32_16x16x32_f16(A, B[mt], acc[mt], 0, 0, 0);
        }
        const int jq = jq0 + l4 * 4;
        float bb[4]; st4(bb, *(const float4*)(b1 + jq));
        #pragma unroll
        for (int mt = 0; mt < 2; ++mt) {
          f16x4 v;
          #pragma unroll
          for (int r = 0; r < 4; ++r) v[r] = (f16)(acc[mt][r] + bb[r]);
          *(f16x4*)(sm + fa32(mt * 16 + l16, jq)) = v;
        }
      }
    }
    __syncthreads();
    // ---- LN(1024) + GELU in place: wave w owns chunks w*8 .. w*8+7 --------
    {
      float s0 = 0.f, q0 = 0.f, s1 = 0.f, q1 = 0.f;
      #pragma unroll
      for (int i = 0; i < 8; ++i) {
        f16x8 v = *(const f16x8*)(sm + (w * 8 + i) * 1024 + lane * 16);
        float ls = 0.f, lq = 0.f;
        #pragma unroll
        for (int j = 0; j < 8; ++j) { float f = (float)v[j]; ls += f; lq += f * f; }
        if (i & 1) { s1 += ls; q1 += lq; } else { s0 += ls; q0 += lq; }
      }
      s0 += __shfl_xor(s0, 16); q0 += __shfl_xor(q0, 16);
      s0 += __shfl_xor(s0, 32); q0 += __shfl_xor(q0, 32);
      s1 += __shfl_xor(s1, 16); q1 += __shfl_xor(q1, 16);
      s1 += __shfl_xor(s1, 32); q1 += __shfl_xor(q1, 32);
      if (l4 == 0) {
        sm_s[l16 * 8 + w] = s0;        sm_ss[l16 * 8 + w] = q0;
        sm_s[(16 + l16) * 8 + w] = s1; sm_ss[(16 + l16) * 8 + w] = q1;
      }
      __syncthreads();
      float mean[2], rstd[2];
      #pragma unroll
      for (int mt = 0; mt < 2; ++mt) {
        const int row = mt * 16 + l16;
        float s = 0.f, q = 0.f;
        #pragma unroll
        for (int i = 0; i < 8; ++i) { s += sm_s[row * 8 + i]; q += sm_ss[row * 8 + i]; }
        mean[mt] = s * (1.f / 1024.f);
        rstd[mt] = rsqrtf(q * (1.f / 1024.f) - mean[mt] * mean[mt] + 1e-5f);
      }
      #pragma unroll 2
      for (int i = 0; i < 8; ++i) {
        const int chunk = w * 8 + i;
        const int off = chunk * 1024 + lane * 16;
        const int c = (chunk >> 1) * 32 + l4 * 8;
        const int mt = i & 1;
        f16x8 v = *(const f16x8*)(sm + off);
        float4 ga = *(const float4*)(g1 + c);
        float4 gb = *(const float4*)(g1 + c + 4);
        float4 ba = *(const float4*)(be1 + c);
        float4 bb = *(const float4*)(be1 + c + 4);
        float gs[8] = {ga.x, ga.y, ga.z, ga.w, gb.x, gb.y, gb.z, gb.w};
        float bs[8] = {ba.x, ba.y, ba.z, ba.w, bb.x, bb.y, bb.z, bb.w};
        f16x8 o;
        #pragma unroll
        for (int j = 0; j < 8; ++j)
          o[j] = (f16)gelu_e(((float)v[j] - mean[mt]) * rstd[mt] * gs[j] + bs[j]);
        *(f16x8*)(sm + off) = o;
      }
    }
    __syncthreads();
    // ---- G0b: h0_half = tanh(t1g @ W2 + b2) -> regs -----------------------
    #pragma unroll
    for (int pp = 0; pp < 4; ++pp) {
      const int jq0 = w * 64 + pp * 16;
      f32x4 acc[2];
      #pragma unroll
      for (int mt = 0; mt < 2; ++mt) acc[mt] = (f32x4){0.f, 0.f, 0.f, 0.f};
      #pragma unroll 2
      for (int kf = 0; kf < 32; ++kf) {
        f16x8 B[2];
        #pragma unroll
        for (int mt = 0; mt < 2; ++mt)
          B[mt] = *(const f16x8*)(sm + (kf * 2 + mt) * 1024 + lane * 16);
        const f16x8 A = *(const f16x8*)(w2t + (jq0 + l16) * 1024 + kf * 32 + l4 * 8);
        #pragma unroll
        for (int mt = 0; mt < 2; ++mt)
          acc[mt] = __builtin_amdgcn_mfma_f32_16x16x32_f16(A, B[mt], acc[mt], 0, 0, 0);
      }
      const int jq = jq0 + l4 * 4;
      float bb[4]; st4(bb, *(const float4*)(b2 + jq));
      #pragma unroll
      for (int mt = 0; mt < 2; ++mt) {
        f16x4 v;
        #pragma unroll
        for (int r = 0; r < 4; ++r) v[r] = (f16)tanh_s(acc[mt][r] + bb[r]);
        h0h[hh][pp][mt] = v;
      }
    }
    __syncthreads();  // all t1 reads done; region reusable
  }
  // ---- commit h0 (frag order, 64 rows) ------------------------------------
  #pragma unroll
  for (int hh = 0; hh < 2; ++hh)
    #pragma unroll
    for (int pp = 0; pp < 4; ++pp) {
      const int jq = w * 64 + pp * 16 + l4 * 4;
      #pragma unroll
      for (int mt = 0; mt < 2; ++mt)
        *(f16x4*)(sm + fa(hh * 32 + mt * 16 + l16, jq)) = h0h[hh][pp][mt];
    }
  __syncthreads();

  // ============================ GRU loop ===================================
  #pragma unroll 1
  for (int t = 0; t < TSTEPS; ++t) {
    // ---- G1: gates = Whh · h^T (4 q-passes), blend -> hnh regs ------------
    f16x4 hnh[4][4];  // [q][mt] — statically indexed (q fully unrolled)
    #pragma unroll
    for (int q = 0; q < 4; ++q) {
      const int jt = w * 64 + q * 16;
      f32x4 acc[4][3];
      #pragma unroll
      for (int mt = 0; mt < 4; ++mt)
        #pragma unroll
        for (int g = 0; g < 3; ++g) acc[mt][g] = (f32x4){0.f, 0.f, 0.f, 0.f};
      #pragma unroll 2
      for (int kf = 0; kf < 16; ++kf) {
        f16x8 B[4];
        #pragma unroll
        for (int mt = 0; mt < 4; ++mt)
          B[mt] = *(const f16x8*)(sm + (kf * 4 + mt) * 1024 + lane * 16);
        #pragma unroll
        for (int g = 0; g < 3; ++g) {
          const f16x8 A = *(const f16x8*)(whh + (g * 512 + jt + l16) * 512 + kf * 32 + l4 * 8);
          #pragma unroll
          for (int mt = 0; mt < 4; ++mt)
            acc[mt][g] = __builtin_amdgcn_mfma_f32_16x16x32_f16(A, B[mt], acc[mt][g], 0, 0, 0);
        }
      }
      if (q == 0) __syncthreads();  // B5: sm_x(t) visible (hidden behind q0 MFMA)
      const int jq = jt + l4 * 4;
      const f16x4 wrh = *(const f16x4*)(c7 + jq);
      const f16x4 wzh = *(const f16x4*)(c7 + 512 + jq);
      const f16x4 wnh = *(const f16x4*)(c7 + 1024 + jq);
      const f16x4 crh = *(const f16x4*)(c7 + 1536 + jq);
      const f16x4 czh = *(const f16x4*)(c7 + 2048 + jq);
      const f16x4 bnh = *(const f16x4*)(c7 + 2560 + jq);
      const f16x4 cnh = *(const f16x4*)(c7 + 3072 + jq);
      #pragma unroll
      for (int mt = 0; mt < 4; ++mt) {
        const int m = mt * 16 + l16;
        const float x = sm_x[m];
        const int hoff = fa(m, jq);
        const f16x4 ho = *(const f16x4*)(sm + hoff);
        f16x4 hn;
        #pragma unroll
        for (int r = 0; r < 4; ++r) {
          const float gr = sigm(x * (float)wrh[r] + (float)crh[r] + acc[mt][0][r]);
          const float gz = sigm(x * (float)wzh[r] + (float)czh[r] + acc[mt][1][r]);
          const float gn = tanh_s(x * (float)wnh[r] + (float)bnh[r] + gr * (acc[mt][2][r] + (float)cnh[r]));
          hn[r] = (f16)((1.f - gz) * gn + gz * (float)ho[r]);
        }
        hnh[q][mt] = hn;
      }
    }
    __syncthreads();  // B1: all reads of h(t) done
    #pragma unroll
    for (int q = 0; q < 4; ++q) {
      const int jq = w * 64 + q * 16 + l4 * 4;
      #pragma unroll
      for (int mt = 0; mt < 4; ++mt)
        *(f16x4*)(sm + fa(mt * 16 + l16, jq)) = hnh[q][mt];
    }
    __syncthreads();  // B2: h(t+1) committed
    // ---- G2: y = gelu(LN(h_new @ Wo1 + bo1)) @ Wo2 + bo2 ------------------
    {
      const int mg = w >> 2, jg = w & 3;   // 2 m-groups x 4 j-groups
      f32x4 a2[2][4];                       // [mi][jt2]
      #pragma unroll
      for (int mi = 0; mi < 2; ++mi)
        #pragma unroll
        for (int jt2 = 0; jt2 < 4; ++jt2) a2[mi][jt2] = (f32x4){0.f, 0.f, 0.f, 0.f};
      #pragma unroll 2
      for (int kf = 0; kf < 16; ++kf) {
        f16x8 B[2];
        #pragma unroll
        for (int mi = 0; mi < 2; ++mi)
          B[mi] = *(const f16x8*)(sm + (kf * 4 + mg * 2 + mi) * 1024 + lane * 16);
        #pragma unroll
        for (int jt2 = 0; jt2 < 4; ++jt2) {
          const f16x8 A = *(const f16x8*)(wo1t + (jg * 64 + jt2 * 16 + l16) * 512 + kf * 32 + l4 * 8);
          #pragma unroll
          for (int mi = 0; mi < 2; ++mi)
            a2[mi][jt2] = __builtin_amdgcn_mfma_f32_16x16x32_f16(A, B[mi], a2[mi][jt2], 0, 0, 0);
        }
      }
      float vv[2][4][4];
      float bo1v[4][4];
      #pragma unroll
      for (int jt2 = 0; jt2 < 4; ++jt2)
        st4(bo1v[jt2], *(const float4*)(bo1 + jg * 64 + jt2 * 16 + l4 * 4));
      #pragma unroll
      for (int mi = 0; mi < 2; ++mi) {
        float s = 0.f, ss = 0.f;
        #pragma unroll
        for (int jt2 = 0; jt2 < 4; ++jt2)
          #pragma unroll
          for (int r = 0; r < 4; ++r) {
            const float v = a2[mi][jt2][r] + bo1v[jt2][r];
            vv[mi][jt2][r] = v; s += v; ss += v * v;
          }
        s += __shfl_xor(s, 16); ss += __shfl_xor(ss, 16);
        s += __shfl_xor(s, 32); ss += __shfl_xor(ss, 32);
        if (l4 == 0) {
          const int m = (mg * 2 + mi) * 16 + l16;
          sm_s[m * 4 + jg] = s;
          sm_ss[m * 4 + jg] = ss;
        }
      }
      __syncthreads();  // B3: stats partials visible
      float gov[4][4], bev[4][4], wv[4][4];
      #pragma unroll
      for (int jt2 = 0; jt2 < 4; ++jt2) {
        const int jb = jg * 64 + jt2 * 16 + l4 * 4;
        st4(gov[jt2], *(const float4*)(go + jb));
        st4(bev[jt2], *(const float4*)(beo + jb));
        st4(wv[jt2], *(const float4*)(Wo2 + jb));
      }
      #pragma unroll
      for (int mi = 0; mi < 2; ++mi) {
        const int m = (mg * 2 + mi) * 16 + l16;
        float4 ps = *(const float4*)(sm_s + m * 4);
        float4 pq = *(const float4*)(sm_ss + m * 4);
        const float mean = (ps.x + ps.y + ps.z + ps.w) * (1.f / 256.f);
        const float q2 = (pq.x + pq.y + pq.z + pq.w) * (1.f / 256.f);
        const float rstd = rsqrtf(q2 - mean * mean + 1e-5f);
        float y = 0.f;
        #pragma unroll
        for (int jt2 = 0; jt2 < 4; ++jt2)
          #pragma unroll
          for (int r = 0; r < 4; ++r)
            y += gelu_e((vv[mi][jt2][r] - mean) * rstd * gov[jt2][r] + bev[jt2][r]) * wv[jt2][r];
        y += __shfl_xor(y, 16);
        y += __shfl_xor(y, 32);
        if (l4 == 0) sm_yp[m * 4 + jg] = y;
      }
      __syncthreads();  // B4: y partials visible
      if (tid < 64) {
        float4 ps = *(const float4*)(sm_yp + tid * 4);
        const float y = bo2v + ps.x + ps.y + ps.z + ps.w;
        sm_x[tid] = y;
        out[(R0 + tid) * 20 + t] = y;
      }
      // next step's B5 (inside q0) covers sm_x visibility
    }
  }
}

// ---------------------------------------------------------------------------
extern "C" void kernel_launch(void* const* d_in, const int* in_sizes, int n_in,
                              void* d_out, int out_size, void* d_ws, size_t ws_size,
                              hipStream_t stream) {
  const float* zq   = (const float*)d_in[0];
  const float* fpr  = (const float*)d_in[1];
  const float* W1   = (const float*)d_in[2];
  const float* b1   = (const float*)d_in[3];
  const float* g1   = (const float*)d_in[4];
  const float* be1  = (const float*)d_in[5];
  const float* W2   = (const float*)d_in[6];
  const float* b2   = (const float*)d_in[7];
  const float* stok = (const float*)d_in[8];
  const float* Wih  = (const float*)d_in[9];
  const float* Whh  = (const float*)d_in[10];
  const float* bih  = (const float*)d_in[11];
  const float* bhh  = (const float*)d_in[12];
  const float* Wo1  = (const float*)d_in[13];
  const float* bo1  = (const float*)d_in[14];
  const float* go   = (const float*)d_in[15];
  const float* beo  = (const float*)d_in[16];
  const float* Wo2  = (const float*)d_in[17];
  const float* bo2  = (const float*)d_in[18];

  char* ws = (char*)d_ws;
  f16* w1t  = (f16*)(ws + 0);        // 1024*160*2  = 327680
  f16* w2t  = (f16*)(ws + 327680);   // 512*1024*2  = 1048576
  f16* whh  = (f16*)(ws + 1376256);  // 1536*512*2  = 1572864
  f16* wo1t = (f16*)(ws + 2949120);  // 256*512*2   = 262144
  f16* c7   = (f16*)(ws + 3211264);  // 7*512*2     = 7168   (total ~3.2MB)

  cvt_weights<<<6287, 256, 0, stream>>>(W1, W2, Whh, Wo1, Wih, bih, bhh,
                                        w1t, w2t, whh, wo1t, c7);

  const int N = in_sizes[0] / 128;  // 65536 rows
  gru_main<<<N / 64, 512, 0, stream>>>(zq, fpr, b1, g1, be1, b2, stok,
                                       bo1, go, beo, Wo2, bo2,
                                       w1t, w2t, whh, wo1t, c7, (float*)d_out);
}

// Round 9
// 5262.464 us; speedup vs baseline: 1.4644x; 1.4644x over previous
//
#include <hip/hip_runtime.h>
#include <math.h>

// ---------------------------------------------------------------------------
// SequencePredictorGRU — fused persistent kernel, fp16 MFMA, fp32 accum.
// R9 = R7 structure (dbuf h in LDS, frag-order, 512thr, LB(512,2) -> ~120 VGPR,
// 1 block/CU, 2 waves/SIMD) + LATENCY FIXES (the R8 post-mortem conclusion:
// all throughput floors ~500us but dur ~6000us -> latency-bound on per-kf
// A-operand L2 loads consumed immediately by MFMA):
//  (1) G1 split into 4 q-passes (acc[4mt][3g]=48 regs, not 96) to free regs;
//  (2) explicit distance-2 register ping-pong prefetch (A0/A1) of the global
//      A-fragments in G1, G2, G0b — ~2 kf-bodies (~400cyc with 2 waves) cover
//      the ~200-300cyc L2 latency;
//  (3) blend coefficients c7[7][512] f16 and G2 epilogue constants staged in
//      LDS once -> blend/epilogue phases have zero global-latency exposure;
//  (4) all cross-iteration register arrays statically indexed (rule #20).
// Frag-order h: chunk((k>>5)*4 + (m>>4))*1024 + ((m&15)+((k>>3)&3)*16)*16
//  + (k&7)*2; B-frag read = base + chunk*1024 + lane*16 (linear, conflict-free).
// MFMA 16x16x32 layouts (verified R1-R8):
//   A: row=l&15, k=(l>>4)*8+i     B: col=l&15, k=(l>>4)*8+i
//   D: col=l&15 (-> m row), row=(l>>4)*4+r (-> j, contiguous quad)
// ---------------------------------------------------------------------------

typedef _Float16 f16;
typedef _Float16 f16x4 __attribute__((ext_vector_type(4)));
typedef _Float16 f16x8 __attribute__((ext_vector_type(8)));
typedef float f32x4 __attribute__((ext_vector_type(4)));

#define TSTEPS 20

__device__ __forceinline__ float sigm(float v) { return 1.0f / (1.0f + __expf(-v)); }
__device__ __forceinline__ float tanh_s(float v) {
  float e = __expf(-2.0f * fabsf(v));
  float r = (1.0f - e) / (1.0f + e);
  return copysignf(r, v);
}
__device__ __forceinline__ float gelu_e(float v) {
  return 0.5f * v * (1.0f + erff(v * 0.70710678118654752f));
}
__device__ __forceinline__ void st4(float* d, float4 v) {
  d[0] = v.x; d[1] = v.y; d[2] = v.z; d[3] = v.w;
}

// frag-order byte address (m,k); h: k<512 (64KB); t1: k<1024 (128KB)
__device__ __forceinline__ int fa(int m, int k) {
  return (((k >> 5) * 4 + (m >> 4)) << 10) + (((m & 15) + ((k >> 3) & 3) * 16) << 4) + ((k & 7) * 2);
}

// ---------------------------------------------------------------------------
// Prologue: fp16 weights (K-contiguous) + packed f16 gate coefficients.
// c7 layout [7][512]: 0 Wih_r, 1 Wih_z, 2 Wih_n, 3 bih_r+bhh_r, 4 bih_z+bhh_z,
//                     5 bih_n, 6 bhh_n
// ---------------------------------------------------------------------------
__global__ void cvt_weights(const float* __restrict__ W1, const float* __restrict__ W2,
                            const float* __restrict__ Whh, const float* __restrict__ Wo1,
                            const float* __restrict__ Wih, const float* __restrict__ bih,
                            const float* __restrict__ bhh,
                            f16* __restrict__ w1t, f16* __restrict__ w2t,
                            f16* __restrict__ whh, f16* __restrict__ wo1t,
                            f16* __restrict__ c7) {
  int i = blockIdx.x * 256 + threadIdx.x;
  if (i < 163840) { int n = i / 160; int k = i - n * 160; w1t[i] = (f16)W1[k * 1024 + n]; return; }
  i -= 163840;
  if (i < 524288) { int n = i >> 10; int k = i & 1023; w2t[i] = (f16)W2[k * 512 + n]; return; }
  i -= 524288;
  if (i < 786432) { whh[i] = (f16)Whh[i]; return; }
  i -= 786432;
  if (i < 131072) { int o = i >> 9; int k = i & 511; wo1t[i] = (f16)Wo1[k * 256 + o]; return; }
  i -= 131072;
  if (i < 3584) {
    const int which = i >> 9, j = i & 511;
    float v;
    if (which == 0) v = Wih[j];
    else if (which == 1) v = Wih[512 + j];
    else if (which == 2) v = Wih[1024 + j];
    else if (which == 3) v = bih[j] + bhh[j];
    else if (which == 4) v = bih[512 + j] + bhh[512 + j];
    else if (which == 5) v = bih[1024 + j];
    else v = bhh[1024 + j];
    c7[i] = (f16)v;
  }
}

// ---------------------------------------------------------------------------
// Main fused kernel: 512 threads = 8 waves, 64 rows/block, 1 block/CU.
// ---------------------------------------------------------------------------
__global__ __launch_bounds__(512, 2)
void gru_main(
    const float* __restrict__ zq, const float* __restrict__ fpr,
    const float* __restrict__ b1, const float* __restrict__ g1, const float* __restrict__ be1,
    const float* __restrict__ b2, const float* __restrict__ stok,
    const float* __restrict__ bo1, const float* __restrict__ go, const float* __restrict__ beo,
    const float* __restrict__ Wo2, const float* __restrict__ bo2,
    const f16* __restrict__ w1t, const f16* __restrict__ w2t,
    const f16* __restrict__ whh, const f16* __restrict__ wo1t,
    const f16* __restrict__ c7,
    float* __restrict__ out) {
  __shared__ __align__(16) unsigned char sm[131072];  // h dbuf 2x64KB / t1 128KB (frag order)
  __shared__ float sm_s[256], sm_ss[256], sm_yp[256];
  __shared__ float sm_x[64];
  __shared__ __align__(8) f16 sm_c7[3584];
  __shared__ __align__(16) float sm_aux[1024];  // bo1|go|beo|Wo2, 256 each

  const int tid = threadIdx.x;
  const int w = tid >> 6;        // 0..7
  const int lane = tid & 63;
  const int l16 = lane & 15;
  const int l4 = lane >> 4;
  const int R0 = blockIdx.x * 64;

  const float bo2v = bo2[0];
  if (tid < 64) sm_x[tid] = stok[0];
  // stage blend coefficients + G2 epilogue constants into LDS (once)
  for (int i = tid; i < 1792; i += 512)
    ((unsigned*)sm_c7)[i] = ((const unsigned*)c7)[i];
  for (int i = tid; i < 1024; i += 512)
    sm_aux[i] = (i < 256) ? bo1[i] : (i < 512) ? go[i - 256] : (i < 768) ? beo[i - 512] : Wo2[i - 768];

  // ================= G0a: t1 = cat(zq,fpr) @ W1 + b1 (frag order) =========
  #pragma unroll 1
  for (int p = 0; p < 4; ++p) {
    #pragma unroll 1
    for (int jh = 0; jh < 2; ++jh) {
      const int jq0 = w * 128 + p * 32 + jh * 16;
      f32x4 acc[4];
      #pragma unroll
      for (int mt = 0; mt < 4; ++mt) acc[mt] = (f32x4){0.f, 0.f, 0.f, 0.f};
      #pragma unroll
      for (int kf = 0; kf < 5; ++kf) {
        const int k0 = kf * 32 + l4 * 8;
        f16x8 B[4];
        #pragma unroll
        for (int mt = 0; mt < 4; ++mt) {
          const int gm = R0 + mt * 16 + l16;
          const float* src = (kf < 4) ? (zq + gm * 128 + k0) : (fpr + gm * 32 + (k0 - 128));
          float4 v0 = *(const float4*)src;
          float4 v1 = *(const float4*)(src + 4);
          f16x8 b;
          b[0] = (f16)v0.x; b[1] = (f16)v0.y; b[2] = (f16)v0.z; b[3] = (f16)v0.w;
          b[4] = (f16)v1.x; b[5] = (f16)v1.y; b[6] = (f16)v1.z; b[7] = (f16)v1.w;
          B[mt] = b;
        }
        const f16x8 A = *(const f16x8*)(w1t + (jq0 + l16) * 160 + k0);
        #pragma unroll
        for (int mt = 0; mt < 4; ++mt)
          acc[mt] = __builtin_amdgcn_mfma_f32_16x16x32_f16(A, B[mt], acc[mt], 0, 0, 0);
      }
      const int jq = jq0 + l4 * 4;
      float bb[4]; st4(bb, *(const float4*)(b1 + jq));
      #pragma unroll
      for (int mt = 0; mt < 4; ++mt) {
        f16x4 v;
        #pragma unroll
        for (int r = 0; r < 4; ++r) v[r] = (f16)(acc[mt][r] + bb[r]);
        *(f16x4*)(sm + fa(mt * 16 + l16, jq)) = v;
      }
    }
  }
  __syncthreads();
  // ================= LN(1024) + GELU in place (frag chunks) ================
  {
    const int mt = w & 3, half = w >> 2;
    const int row = mt * 16 + l16;
    float s = 0.f, ss = 0.f;
    #pragma unroll 4
    for (int it = 0; it < 16; ++it) {
      const int kb = half * 16 + it;
      f16x8 v = *(const f16x8*)(sm + (kb * 4 + mt) * 1024 + lane * 16);
      #pragma unroll
      for (int i = 0; i < 8; ++i) { float f = (float)v[i]; s += f; ss += f * f; }
    }
    s += __shfl_xor(s, 16); ss += __shfl_xor(ss, 16);
    s += __shfl_xor(s, 32); ss += __shfl_xor(ss, 32);
    if (l4 == 0) { sm_s[row * 2 + half] = s; sm_ss[row * 2 + half] = ss; }
    __syncthreads();
    const float mean = (sm_s[row * 2] + sm_s[row * 2 + 1]) * (1.f / 1024.f);
    const float q2 = (sm_ss[row * 2] + sm_ss[row * 2 + 1]) * (1.f / 1024.f);
    const float rstd = rsqrtf(q2 - mean * mean + 1e-5f);
    #pragma unroll 2
    for (int it = 0; it < 16; ++it) {
      const int kb = half * 16 + it;
      const int off = (kb * 4 + mt) * 1024 + lane * 16;
      const int c = kb * 32 + l4 * 8;
      f16x8 v = *(const f16x8*)(sm + off);
      float4 ga = *(const float4*)(g1 + c);
      float4 gb = *(const float4*)(g1 + c + 4);
      float4 ba = *(const float4*)(be1 + c);
      float4 bb = *(const float4*)(be1 + c + 4);
      float gs[8] = {ga.x, ga.y, ga.z, ga.w, gb.x, gb.y, gb.z, gb.w};
      float bs[8] = {ba.x, ba.y, ba.z, ba.w, bb.x, bb.y, bb.z, bb.w};
      f16x8 o;
      #pragma unroll
      for (int j = 0; j < 8; ++j)
        o[j] = (f16)gelu_e(((float)v[j] - mean) * rstd * gs[j] + bs[j]);
      *(f16x8*)(sm + off) = o;
    }
  }
  __syncthreads();
  // ================= G0b: h0 = tanh(t1g @ W2 + b2) -> regs (prefetched) ====
  f16x4 hold[4][4];  // [pp][mt] — pp fully unrolled (static indexing)
  #pragma unroll
  for (int pp = 0; pp < 4; ++pp) {
    const f16* Ab = w2t + (w * 64 + pp * 16 + l16) * 1024 + l4 * 8;
    f32x4 acc[4];
    #pragma unroll
    for (int mt = 0; mt < 4; ++mt) acc[mt] = (f32x4){0.f, 0.f, 0.f, 0.f};
    f16x8 A0 = *(const f16x8*)(Ab);
    f16x8 A1 = *(const f16x8*)(Ab + 32);
    #pragma unroll 1
    for (int kp = 0; kp < 16; ++kp) {
      {
        f16x8 B[4];
        #pragma unroll
        for (int mt = 0; mt < 4; ++mt)
          B[mt] = *(const f16x8*)(sm + ((kp * 8 + mt) << 10) + lane * 16);
        #pragma unroll
        for (int mt = 0; mt < 4; ++mt)
          acc[mt] = __builtin_amdgcn_mfma_f32_16x16x32_f16(A0, B[mt], acc[mt], 0, 0, 0);
        if (kp < 15) A0 = *(const f16x8*)(Ab + (kp * 2 + 2) * 32);
      }
      {
        f16x8 B[4];
        #pragma unroll
        for (int mt = 0; mt < 4; ++mt)
          B[mt] = *(const f16x8*)(sm + ((kp * 8 + 4 + mt) << 10) + lane * 16);
        #pragma unroll
        for (int mt = 0; mt < 4; ++mt)
          acc[mt] = __builtin_amdgcn_mfma_f32_16x16x32_f16(A1, B[mt], acc[mt], 0, 0, 0);
        if (kp < 15) A1 = *(const f16x8*)(Ab + (kp * 2 + 3) * 32);
      }
    }
    const int jq = w * 64 + pp * 16 + l4 * 4;
    float bb[4]; st4(bb, *(const float4*)(b2 + jq));
    #pragma unroll
    for (int mt = 0; mt < 4; ++mt) {
      f16x4 v;
      #pragma unroll
      for (int r = 0; r < 4; ++r) v[r] = (f16)tanh_s(acc[mt][r] + bb[r]);
      hold[pp][mt] = v;
    }
  }
  __syncthreads();  // all t1 reads done; region reusable as h buffers
  #pragma unroll
  for (int pp = 0; pp < 4; ++pp) {
    const int jq = w * 64 + pp * 16 + l4 * 4;
    #pragma unroll
    for (int mt = 0; mt < 4; ++mt)
      *(f16x4*)(sm + fa(mt * 16 + l16, jq)) = hold[pp][mt];
  }
  __syncthreads();

  // ============================ GRU loop ===================================
  #pragma unroll 1
  for (int t = 0; t < TSTEPS; ++t) {
    const int cur = (t & 1) << 16;
    const int nxt = cur ^ 65536;
    // ---- G1: gates = Whh · h^T, 4 q-passes, distance-2 A prefetch ---------
    #pragma unroll 1
    for (int q = 0; q < 4; ++q) {
      const int jt = w * 64 + q * 16;
      const f16* Ab = whh + (jt + l16) * 512 + l4 * 8;
      f32x4 acc[4][3];
      #pragma unroll
      for (int mt = 0; mt < 4; ++mt)
        #pragma unroll
        for (int g = 0; g < 3; ++g) acc[mt][g] = (f32x4){0.f, 0.f, 0.f, 0.f};
      f16x8 A0[3], A1[3];
      #pragma unroll
      for (int g = 0; g < 3; ++g) A0[g] = *(const f16x8*)(Ab + g * 262144);
      #pragma unroll
      for (int g = 0; g < 3; ++g) A1[g] = *(const f16x8*)(Ab + g * 262144 + 32);
      #pragma unroll 1
      for (int kp = 0; kp < 8; ++kp) {
        {
          f16x8 B[4];
          #pragma unroll
          for (int mt = 0; mt < 4; ++mt)
            B[mt] = *(const f16x8*)(sm + cur + ((kp * 8 + mt) << 10) + lane * 16);
          #pragma unroll
          for (int g = 0; g < 3; ++g)
            #pragma unroll
            for (int mt = 0; mt < 4; ++mt)
              acc[mt][g] = __builtin_amdgcn_mfma_f32_16x16x32_f16(A0[g], B[mt], acc[mt][g], 0, 0, 0);
          if (kp < 7) {
            #pragma unroll
            for (int g = 0; g < 3; ++g)
              A0[g] = *(const f16x8*)(Ab + g * 262144 + (kp * 2 + 2) * 32);
          }
        }
        {
          f16x8 B[4];
          #pragma unroll
          for (int mt = 0; mt < 4; ++mt)
            B[mt] = *(const f16x8*)(sm + cur + ((kp * 8 + 4 + mt) << 10) + lane * 16);
          #pragma unroll
          for (int g = 0; g < 3; ++g)
            #pragma unroll
            for (int mt = 0; mt < 4; ++mt)
              acc[mt][g] = __builtin_amdgcn_mfma_f32_16x16x32_f16(A1[g], B[mt], acc[mt][g], 0, 0, 0);
          if (kp < 7) {
            #pragma unroll
            for (int g = 0; g < 3; ++g)
              A1[g] = *(const f16x8*)(Ab + g * 262144 + (kp * 2 + 3) * 32);
          }
        }
      }
      if (q == 0) __syncthreads();  // B5: sm_x(t) visible (hidden behind q0 MFMA)
      const int jq = jt + l4 * 4;
      const f16x4 wrh = *(const f16x4*)(sm_c7 + jq);
      const f16x4 wzh = *(const f16x4*)(sm_c7 + 512 + jq);
      const f16x4 wnh = *(const f16x4*)(sm_c7 + 1024 + jq);
      const f16x4 crh = *(const f16x4*)(sm_c7 + 1536 + jq);
      const f16x4 czh = *(const f16x4*)(sm_c7 + 2048 + jq);
      const f16x4 bnh = *(const f16x4*)(sm_c7 + 2560 + jq);
      const f16x4 cnh = *(const f16x4*)(sm_c7 + 3072 + jq);
      #pragma unroll
      for (int mt = 0; mt < 4; ++mt) {
        const int m = mt * 16 + l16;
        const float x = sm_x[m];
        const int hoff = fa(m, jq);
        const f16x4 ho = *(const f16x4*)(sm + cur + hoff);
        f16x4 hn;
        #pragma unroll
        for (int r = 0; r < 4; ++r) {
          const float gr = sigm(x * (float)wrh[r] + (float)crh[r] + acc[mt][0][r]);
          const float gz = sigm(x * (float)wzh[r] + (float)czh[r] + acc[mt][1][r]);
          const float gn = tanh_s(x * (float)wnh[r] + (float)bnh[r] + gr * (acc[mt][2][r] + (float)cnh[r]));
          hn[r] = (f16)((1.f - gz) * gn + gz * (float)ho[r]);
        }
        *(f16x4*)(sm + nxt + hoff) = hn;
      }
    }
    __syncthreads();  // B2: h[nxt] complete
    // ---- G2: y = gelu(LN(h_new @ Wo1 + bo1)) @ Wo2 + bo2 (prefetched) -----
    {
      const int mg = w >> 2, jg = w & 3;   // 2 m-groups x 4 j-groups
      const f16* Ab2 = wo1t + (jg * 64 + l16) * 512 + l4 * 8;
      f32x4 a2[2][4];                       // [mi][jt2]
      #pragma unroll
      for (int mi = 0; mi < 2; ++mi)
        #pragma unroll
        for (int jt2 = 0; jt2 < 4; ++jt2) a2[mi][jt2] = (f32x4){0.f, 0.f, 0.f, 0.f};
      f16x8 C0[4], C1[4];
      #pragma unroll
      for (int jt2 = 0; jt2 < 4; ++jt2) C0[jt2] = *(const f16x8*)(Ab2 + jt2 * 8192);
      #pragma unroll
      for (int jt2 = 0; jt2 < 4; ++jt2) C1[jt2] = *(const f16x8*)(Ab2 + jt2 * 8192 + 32);
      #pragma unroll 1
      for (int kp = 0; kp < 8; ++kp) {
        {
          f16x8 B[2];
          #pragma unroll
          for (int mi = 0; mi < 2; ++mi)
            B[mi] = *(const f16x8*)(sm + nxt + ((kp * 8 + mg * 2 + mi) << 10) + lane * 16);
          #pragma unroll
          for (int jt2 = 0; jt2 < 4; ++jt2)
            #pragma unroll
            for (int mi = 0; mi < 2; ++mi)
              a2[mi][jt2] = __builtin_amdgcn_mfma_f32_16x16x32_f16(C0[jt2], B[mi], a2[mi][jt2], 0, 0, 0);
          if (kp < 7) {
            #pragma unroll
            for (int jt2 = 0; jt2 < 4; ++jt2)
              C0[jt2] = *(const f16x8*)(Ab2 + jt2 * 8192 + (kp * 2 + 2) * 32);
          }
        }
        {
          f16x8 B[2];
          #pragma unroll
          for (int mi = 0; mi < 2; ++mi)
            B[mi] = *(const f16x8*)(sm + nxt + ((kp * 8 + 4 + mg * 2 + mi) << 10) + lane * 16);
          #pragma unroll
          for (int jt2 = 0; jt2 < 4; ++jt2)
            #pragma unroll
            for (int mi = 0; mi < 2; ++mi)
              a2[mi][jt2] = __builtin_amdgcn_mfma_f32_16x16x32_f16(C1[jt2], B[mi], a2[mi][jt2], 0, 0, 0);
          if (kp < 7) {
            #pragma unroll
            for (int jt2 = 0; jt2 < 4; ++jt2)
              C1[jt2] = *(const f16x8*)(Ab2 + jt2 * 8192 + (kp * 2 + 3) * 32);
          }
        }
      }
      float vv[2][4][4];
      float bo1v[4][4];
      #pragma unroll
      for (int jt2 = 0; jt2 < 4; ++jt2)
        st4(bo1v[jt2], *(const float4*)(sm_aux + jg * 64 + jt2 * 16 + l4 * 4));
      #pragma unroll
      for (int mi = 0; mi < 2; ++mi) {
        float s = 0.f, ss = 0.f;
        #pragma unroll
        for (int jt2 = 0; jt2 < 4; ++jt2)
          #pragma unroll
          for (int r = 0; r < 4; ++r) {
            const float v = a2[mi][jt2][r] + bo1v[jt2][r];
            vv[mi][jt2][r] = v; s += v; ss += v * v;
          }
        s += __shfl_xor(s, 16); ss += __shfl_xor(ss, 16);
        s += __shfl_xor(s, 32); ss += __shfl_xor(ss, 32);
        if (l4 == 0) {
          const int m = (mg * 2 + mi) * 16 + l16;
          sm_s[m * 4 + jg] = s;
          sm_ss[m * 4 + jg] = ss;
        }
      }
      __syncthreads();  // B3: stats partials visible
      float gov[4][4], bev[4][4], wv[4][4];
      #pragma unroll
      for (int jt2 = 0; jt2 < 4; ++jt2) {
        const int jb = jg * 64 + jt2 * 16 + l4 * 4;
        st4(gov[jt2], *(const float4*)(sm_aux + 256 + jb));
        st4(bev[jt2], *(const float4*)(sm_aux + 512 + jb));
        st4(wv[jt2], *(const float4*)(sm_aux + 768 + jb));
      }
      #pragma unroll
      for (int mi = 0; mi < 2; ++mi) {
        const int m = (mg * 2 + mi) * 16 + l16;
        float4 ps = *(const float4*)(sm_s + m * 4);
        float4 pq = *(const float4*)(sm_ss + m * 4);
        const float mean = (ps.x + ps.y + ps.z + ps.w) * (1.f / 256.f);
        const float q2 = (pq.x + pq.y + pq.z + pq.w) * (1.f / 256.f);
        const float rstd = rsqrtf(q2 - mean * mean + 1e-5f);
        float y = 0.f;
        #pragma unroll
        for (int jt2 = 0; jt2 < 4; ++jt2)
          #pragma unroll
          for (int r = 0; r < 4; ++r)
            y += gelu_e((vv[mi][jt2][r] - mean) * rstd * gov[jt2][r] + bev[jt2][r]) * wv[jt2][r];
        y += __shfl_xor(y, 16);
        y += __shfl_xor(y, 32);
        if (l4 == 0) sm_yp[m * 4 + jg] = y;
      }
      __syncthreads();  // B4: y partials visible
      if (tid < 64) {
        float4 ps = *(const float4*)(sm_yp + tid * 4);
        const float y = bo2v + ps.x + ps.y + ps.z + ps.w;
        sm_x[tid] = y;
        out[(R0 + tid) * 20 + t] = y;
      }
      // next step's B5 (inside q0) covers sm_x visibility
    }
  }
}

// ---------------------------------------------------------------------------
extern "C" void kernel_launch(void* const* d_in, const int* in_sizes, int n_in,
                              void* d_out, int out_size, void* d_ws, size_t ws_size,
                              hipStream_t stream) {
  const float* zq   = (const float*)d_in[0];
  const float* fpr  = (const float*)d_in[1];
  const float* W1   = (const float*)d_in[2];
  const float* b1   = (const float*)d_in[3];
  const float* g1   = (const float*)d_in[4];
  const float* be1  = (const float*)d_in[5];
  const float* W2   = (const float*)d_in[6];
  const float* b2   = (const float*)d_in[7];
  const float* stok = (const float*)d_in[8];
  const float* Wih  = (const float*)d_in[9];
  const float* Whh  = (const float*)d_in[10];
  const float* bih  = (const float*)d_in[11];
  const float* bhh  = (const float*)d_in[12];
  const float* Wo1  = (const float*)d_in[13];
  const float* bo1  = (const float*)d_in[14];
  const float* go   = (const float*)d_in[15];
  const float* beo  = (const float*)d_in[16];
  const float* Wo2  = (const float*)d_in[17];
  const float* bo2  = (const float*)d_in[18];

  char* ws = (char*)d_ws;
  f16* w1t  = (f16*)(ws + 0);        // 1024*160*2  = 327680
  f16* w2t  = (f16*)(ws + 327680);   // 512*1024*2  = 1048576
  f16* whh  = (f16*)(ws + 1376256);  // 1536*512*2  = 1572864
  f16* wo1t = (f16*)(ws + 2949120);  // 256*512*2   = 262144
  f16* c7   = (f16*)(ws + 3211264);  // 7*512*2     = 7168   (total ~3.2MB)

  cvt_weights<<<6287, 256, 0, stream>>>(W1, W2, Whh, Wo1, Wih, bih, bhh,
                                        w1t, w2t, whh, wo1t, c7);

  const int N = in_sizes[0] / 128;  // 65536 rows
  gru_main<<<N / 64, 512, 0, stream>>>(zq, fpr, b1, g1, be1, b2, stok,
                                       bo1, go, beo, Wo2, bo2,
                                       w1t, w2t, whh, wo1t, c7, (float*)d_out);
}